// Round 8
// baseline (64.836 us; speedup 1.0000x reference)
//
#include <hip/hip_runtime.h>
#include <math.h>

// PatchNorm forward (training-mode Welford update + normalize), 3 kernels.
// Round-7 lesson: fused per-cell kernel = phase lockstep at exactly-full
// residency -> HBM duty cycle ~40%. Split into homogeneous kernels:
//   k_pf:      pack per-token cell id (0xFFFF = padded)           [tiny]
//   k_moments: per-cell scan+gather, predicated 4-deep batches,
//              closed-form stats -> mean_new/inv_std (2 MB)       [read-heavy]
//   k_norm:    sequential patches re-read (L3-hot) + sequential
//              out write; stats gathered from L2; pads zeroed     [write-heavy]
//
// Closed-form per-cell moments (n_g uniform within a cell):
//   mean_new = mo + (S1 - cnt*mo)/n_g                 S1 = sum_valid xbar
//   m2_new   = m2 + S2 - (mo+mn)*S1 + cnt*mo*mn       S2 = sum_valid xbar^2

#define EPSF 1e-6f

static constexpr int W_GRID  = 32;    // grid width (pf = pos_h*W + pos_w)
static constexpr int P2      = 256;   // patch_res^2
static constexpr int P4      = 64;    // P2/4
static constexpr int D4      = 192;   // D/4 float4 chunks per token
static constexpr int HW      = 1024;  // grid cells
static constexpr int NTOK    = 32768; // tokens
static constexpr int LISTCAP = 96;    // token-list capacity (E[cnt]=28.8, max~50)

// ---- kernel 1: pack per-token cell id (0xFFFF = padded) --------------------
__global__ void k_pf(const int* __restrict__ pos_h,
                     const int* __restrict__ pos_w,
                     const int* __restrict__ mask,
                     unsigned short* __restrict__ pf16) {
    int i = blockIdx.x * blockDim.x + threadIdx.x;
    if (i >= NTOK) return;
    const int valid = (mask[i] == 0);
    pf16[i] = valid ? (unsigned short)(pos_h[i] * W_GRID + pos_w[i])
                    : (unsigned short)0xFFFF;
}

// ---- kernel 2: per-cell moments + stats (one block per cell) ---------------
__global__ void __launch_bounds__(256, 4)
k_moments(const float4* __restrict__ patches4,
          const unsigned short* __restrict__ pf16,
          const float* __restrict__ n_old,
          const float* __restrict__ mean_old,
          const float* __restrict__ m2_old,
          float* __restrict__ mean_new,
          float* __restrict__ inv_std) {
    const int g    = blockIdx.x;
    const int tid  = threadIdx.x;
    const int wave = tid >> 6;
    const int lane = tid & 63;

    __shared__ int    list[LISTCAP];
    __shared__ int    s_cnt;
    __shared__ float4 l14[4][64];
    __shared__ float4 l24[4][64];

    if (tid == 0) s_cnt = 0;

    // issue all scan loads up front (16 independent L2 loads in flight)
    const int4* pp = (const int4*)pf16;
    int4 v[16];
#pragma unroll
    for (int it = 0; it < 16; ++it) v[it] = pp[it * 256 + tid];
    __syncthreads();

#pragma unroll
    for (int it = 0; it < 16; ++it) {
        const int base = (it * 256 + tid) * 8;
#pragma unroll
        for (int k = 0; k < 4; ++k) {
            const int word = (&v[it].x)[k];
            const int g0 = word & 0xFFFF;
            const int g1 = (word >> 16) & 0xFFFF;
            if (g0 == g) { int s = atomicAdd(&s_cnt, 1); if (s < LISTCAP) list[s] = base + 2 * k; }
            if (g1 == g) { int s = atomicAdd(&s_cnt, 1); if (s < LISTCAP) list[s] = base + 2 * k + 1; }
        }
    }
    __syncthreads();
    const int c = min(s_cnt, LISTCAP);

    // gather: S1/S2 moments, predicated 4-deep batches ONLY (no serial tail)
    float4 s1 = make_float4(0.f, 0.f, 0.f, 0.f);
    float4 s2 = make_float4(0.f, 0.f, 0.f, 0.f);
    for (int k = wave; k < c; k += 16) {
        int   idx[4];
        float wf[4];
#pragma unroll
        for (int j = 0; j < 4; ++j) {
            const int  kk  = k + 4 * j;
            const bool val = (kk < c);
            wf[j]  = val ? 1.0f : 0.0f;
            idx[j] = list[val ? kk : k];     // k itself is always < c
        }
        float4 A[4], B[4], Dd[4];
#pragma unroll
        for (int j = 0; j < 4; ++j) {
            const float4* tp = patches4 + (size_t)idx[j] * D4;
            A[j]  = tp[lane];
            B[j]  = tp[lane + P4];
            Dd[j] = tp[lane + 2 * P4];
        }
#pragma unroll
        for (int j = 0; j < 4; ++j) {
            const float f = (1.0f / 3.0f) * wf[j];
            float4 xb;
            xb.x = (A[j].x + B[j].x + Dd[j].x) * f;
            xb.y = (A[j].y + B[j].y + Dd[j].y) * f;
            xb.z = (A[j].z + B[j].z + Dd[j].z) * f;
            xb.w = (A[j].w + B[j].w + Dd[j].w) * f;
            s1.x += xb.x; s1.y += xb.y; s1.z += xb.z; s1.w += xb.w;
            s2.x += xb.x * xb.x; s2.y += xb.y * xb.y;
            s2.z += xb.z * xb.z; s2.w += xb.w * xb.w;   // wf^2 == wf
        }
    }

    // cross-wave reduce + closed-form stats (tid = p index)
    l14[wave][lane] = s1;
    l24[wave][lane] = s2;
    __syncthreads();

    const float* l1f = (const float*)l14;
    const float* l2f = (const float*)l24;
    const float S1 = l1f[tid] + l1f[256 + tid] + l1f[512 + tid] + l1f[768 + tid];
    const float S2 = l2f[tid] + l2f[256 + tid] + l2f[512 + tid] + l2f[768 + tid];

    const float cnt = (float)c;
    const float nn  = n_old[g] + cnt;
    const float ng  = fmaxf(nn, 1.0f);
    const int   j   = g * P2 + tid;
    const float mo  = mean_old[j];
    const float mn  = mo + (S1 - cnt * mo) / ng;
    const float m2n = m2_old[j] + (S2 - (mo + mn) * S1 + cnt * mo * mn);
    const float var = (nn < 2.0f) ? 1.0f : (m2n / ng);
    mean_new[j] = mn;
    inv_std[j]  = 1.0f / (sqrtf(var) + EPSF);
}

// ---- kernel 3: sequential normalize ----------------------------------------
// 4096 blocks x 256 threads; block b owns chunk range [b*1536, (b+1)*1536)
// = tokens [8b, 8b+8). Thread handles 6 float4 chunks at stride 256.
static constexpr int CPB = 1536;   // float4 chunks per block (= 8 tokens)
__global__ void __launch_bounds__(256, 4)
k_norm(const float4* __restrict__ patches4,
       const unsigned short* __restrict__ pf16,
       const float4* __restrict__ mn4,
       const float4* __restrict__ is4,
       float4* __restrict__ out4) {
    const int b    = blockIdx.x;
    const int tid  = threadIdx.x;
    const int cbase = b * CPB;
    const int tok0  = b * 8;

    __shared__ unsigned short s_gg[8];
    if (tid < 8) s_gg[tid] = pf16[tok0 + tid];

    // issue all 6 patch loads up front (sequential, coalesced)
    float4 x[6];
#pragma unroll
    for (int j = 0; j < 6; ++j) x[j] = patches4[cbase + j * 256 + tid];
    __syncthreads();

    int   gx[6], pidx[6];
    float wv[6];
#pragma unroll
    for (int j = 0; j < 6; ++j) {
        const int local = j * 256 + tid;      // 0..1535
        const int lt    = local / 192;        // local token 0..7 (const-div)
        pidx[j] = (local - lt * 192) & 63;    // p4 within cell row
        const unsigned short gg = s_gg[lt];
        wv[j] = (gg != 0xFFFF) ? 1.0f : 0.0f;
        gx[j] = (gg != 0xFFFF) ? (int)gg : 0;
    }

    float4 m[6], s[6];
#pragma unroll
    for (int j = 0; j < 6; ++j) {
        m[j] = mn4[gx[j] * P4 + pidx[j]];
        s[j] = is4[gx[j] * P4 + pidx[j]];
    }
#pragma unroll
    for (int j = 0; j < 6; ++j) {
        float4 o;
        o.x = (x[j].x - m[j].x) * s[j].x * wv[j];
        o.y = (x[j].y - m[j].y) * s[j].y * wv[j];
        o.z = (x[j].z - m[j].z) * s[j].z * wv[j];
        o.w = (x[j].w - m[j].w) * s[j].w * wv[j];
        out4[cbase + j * 256 + tid] = o;
    }
}

extern "C" void kernel_launch(void* const* d_in, const int* in_sizes, int n_in,
                              void* d_out, int out_size, void* d_ws, size_t ws_size,
                              hipStream_t stream) {
    const float4* patches4 = (const float4*)d_in[0];
    const int*    pos_h    = (const int*)d_in[1];
    const int*    pos_w    = (const int*)d_in[2];
    const int*    mask     = (const int*)d_in[3];
    const float*  n_old    = (const float*)d_in[4];
    const float*  mean     = (const float*)d_in[5];
    const float*  m2       = (const float*)d_in[6];
    float4* out4 = (float4*)d_out;

    // workspace: ushort pf16[NTOK] (64 KB) | f32 mean_new[HW*P2] | inv_std[HW*P2]
    unsigned short* pf16 = (unsigned short*)d_ws;
    float* mean_new = (float*)(pf16 + NTOK);
    float* inv_std  = mean_new + (size_t)HW * P2;

    k_pf<<<NTOK / 256, 256, 0, stream>>>(pos_h, pos_w, mask, pf16);
    k_moments<<<HW, 256, 0, stream>>>(patches4, pf16, n_old, mean, m2,
                                      mean_new, inv_std);
    k_norm<<<(NTOK * D4) / CPB, 256, 0, stream>>>(patches4, pf16,
                                                  (const float4*)mean_new,
                                                  (const float4*)inv_std, out4);
}

// Round 9
// 59.387 us; speedup vs baseline: 1.0917x; 1.0917x over previous
//
#include <hip/hip_runtime.h>
#include <math.h>

// PatchNorm forward (training-mode Welford update + normalize), 2 kernels:
//   k_pf:   pack per-token cell id into ushort (0xFFFF = padded)
//   k_cell: one block per grid cell -- scan pf16 -> token list in LDS ->
//           gather rows (8-deep pinned load batches) -> closed-form stats in
//           LDS -> normalize the SAME rows (4-deep pinned batches).
// Round-8 lesson: kernel split loses fused L2 locality (58.9->64.8us). Fused
// is right; the 33%-HBM stall was MLP: VGPR=40 showed the compiler kept only
// ~5 loads in flight (Little's law -> 2.7 TB/s, as measured). This version
// pins load batches with sched_barrier(0) so all loads issue before any use.
//
// Closed-form per-cell moments (n_g uniform within a cell):
//   mean_new = mo + (S1 - cnt*mo)/n_g                 S1 = sum_valid xbar
//   m2_new   = m2 + S2 - (mo+mn)*S1 + cnt*mo*mn       S2 = sum_valid xbar^2

#define EPSF 1e-6f

static constexpr int W_GRID  = 32;    // grid width (pf = pos_h*W + pos_w)
static constexpr int P2      = 256;   // patch_res^2
static constexpr int P4      = 64;    // P2/4
static constexpr int D4      = 192;   // D/4 float4 chunks per token
static constexpr int HW      = 1024;  // grid cells
static constexpr int NTOK    = 32768; // tokens
static constexpr int LISTCAP = 96;    // token-list capacity (E[cnt]=28.8, max~50)
static constexpr int SLICE   = NTOK / HW; // 32 tokens/block for pad-zeroing

// ---- kernel 1: pack per-token cell id (0xFFFF = padded) --------------------
__global__ void k_pf(const int* __restrict__ pos_h,
                     const int* __restrict__ pos_w,
                     const int* __restrict__ mask,
                     unsigned short* __restrict__ pf16) {
    int i = blockIdx.x * blockDim.x + threadIdx.x;
    if (i >= NTOK) return;
    const int valid = (mask[i] == 0);
    pf16[i] = valid ? (unsigned short)(pos_h[i] * W_GRID + pos_w[i])
                    : (unsigned short)0xFFFF;
}

// ---- kernel 2: fused per-cell moments + stats + normalize ------------------
__global__ void __launch_bounds__(256, 4)
k_cell(const float4* __restrict__ patches4,
       const unsigned short* __restrict__ pf16,
       const float* __restrict__ n_old,
       const float* __restrict__ mean_old,
       const float* __restrict__ m2_old,
       float4* __restrict__ out4) {
    const int g    = blockIdx.x;
    const int tid  = threadIdx.x;
    const int wave = tid >> 6;
    const int lane = tid & 63;

    __shared__ int            list[LISTCAP];
    __shared__ int            s_cnt;
    __shared__ unsigned short s_slice[SLICE];
    __shared__ float4         l14[4][64];
    __shared__ float4         l24[4][64];
    __shared__ float4         mn_s[P4];
    __shared__ float4         is_s[P4];

    if (tid == 0) s_cnt = 0;
    if (tid < SLICE) s_slice[tid] = pf16[g * SLICE + tid];

    // ---- issue ALL scan loads up front (16 independent L2 loads in flight) -
    const int4* pp = (const int4*)pf16;
    int4 v[16];
#pragma unroll
    for (int it = 0; it < 16; ++it) v[it] = pp[it * 256 + tid];

    __syncthreads();

    // ---- pad-zeroing for this block's 32-token slice -----------------------
#pragma unroll
    for (int t = 0; t < SLICE; ++t) {
        if (s_slice[t] == 0xFFFF) {
            const int i = g * SLICE + t;
            if (tid < D4)
                out4[(size_t)i * D4 + tid] = make_float4(0.f, 0.f, 0.f, 0.f);
        }
    }

    // ---- process scan chunks -> LDS token list -----------------------------
#pragma unroll
    for (int it = 0; it < 16; ++it) {
        const int base = (it * 256 + tid) * 8;
#pragma unroll
        for (int k = 0; k < 4; ++k) {
            const int word = (&v[it].x)[k];
            const int g0 = word & 0xFFFF;
            const int g1 = (word >> 16) & 0xFFFF;
            if (g0 == g) { int s = atomicAdd(&s_cnt, 1); if (s < LISTCAP) list[s] = base + 2 * k; }
            if (g1 == g) { int s = atomicAdd(&s_cnt, 1); if (s < LISTCAP) list[s] = base + 2 * k + 1; }
        }
    }
    __syncthreads();
    const int c = min(s_cnt, LISTCAP);

    // ---- gather: S1/S2 moments, 8 tokens (24 loads) pinned in flight -------
    float4 s1 = make_float4(0.f, 0.f, 0.f, 0.f);
    float4 s2 = make_float4(0.f, 0.f, 0.f, 0.f);
    for (int k = wave; k < c; k += 32) {
        int   idx[8];
        float wf[8];
#pragma unroll
        for (int j = 0; j < 8; ++j) {
            const int  kk  = k + 4 * j;
            const bool val = (kk < c);
            wf[j]  = val ? 1.0f : 0.0f;
            idx[j] = list[val ? kk : k];      // k itself is always < c
        }
        float4 A[8], Bv[8], Dv[8];
#pragma unroll
        for (int j = 0; j < 8; ++j) {
            const float4* tp = patches4 + (size_t)idx[j] * D4 + lane;
            A[j]  = tp[0];
            Bv[j] = tp[P4];
            Dv[j] = tp[2 * P4];
        }
        __builtin_amdgcn_sched_barrier(0);    // pin: all 24 loads before uses
#pragma unroll
        for (int j = 0; j < 8; ++j) {
            const float f = (1.0f / 3.0f) * wf[j];
            float4 xb;
            xb.x = (A[j].x + Bv[j].x + Dv[j].x) * f;
            xb.y = (A[j].y + Bv[j].y + Dv[j].y) * f;
            xb.z = (A[j].z + Bv[j].z + Dv[j].z) * f;
            xb.w = (A[j].w + Bv[j].w + Dv[j].w) * f;
            s1.x += xb.x; s1.y += xb.y; s1.z += xb.z; s1.w += xb.w;
            s2.x += xb.x * xb.x; s2.y += xb.y * xb.y;
            s2.z += xb.z * xb.z; s2.w += xb.w * xb.w;   // wf^2 == wf
        }
    }

    // ---- cross-wave reduce + closed-form stats (tid = p index) -------------
    l14[wave][lane] = s1;
    l24[wave][lane] = s2;
    __syncthreads();

    {
        const float* l1f = (const float*)l14;
        const float* l2f = (const float*)l24;
        const float S1 = l1f[tid] + l1f[256 + tid] + l1f[512 + tid] + l1f[768 + tid];
        const float S2 = l2f[tid] + l2f[256 + tid] + l2f[512 + tid] + l2f[768 + tid];

        const float cnt = (float)c;
        const float nn  = n_old[g] + cnt;
        const float ng  = fmaxf(nn, 1.0f);
        const int   j   = g * P2 + tid;
        const float mo  = mean_old[j];
        const float mn  = mo + (S1 - cnt * mo) / ng;
        const float m2n = m2_old[j] + (S2 - (mo + mn) * S1 + cnt * mo * mn);
        const float var = (nn < 2.0f) ? 1.0f : (m2n / ng);
        ((float*)mn_s)[tid] = mn;
        ((float*)is_s)[tid] = 1.0f / (sqrtf(var) + EPSF);
    }
    __syncthreads();

    // ---- normalize the same rows, 4 tokens (12 loads) pinned in flight -----
    const float4 m4 = mn_s[lane];
    const float4 s4 = is_s[lane];
    for (int k = wave; k < c; k += 16) {
        int  idx[4];
        bool val[4];
#pragma unroll
        for (int j = 0; j < 4; ++j) {
            const int kk = k + 4 * j;
            val[j] = (kk < c);                // wave-uniform predicate
            idx[j] = list[val[j] ? kk : k];
        }
        float4 X[12];
#pragma unroll
        for (int j = 0; j < 4; ++j) {
            const float4* tp = patches4 + (size_t)idx[j] * D4 + lane;
            X[3 * j]     = tp[0];
            X[3 * j + 1] = tp[P4];
            X[3 * j + 2] = tp[2 * P4];
        }
        __builtin_amdgcn_sched_barrier(0);    // pin: all 12 loads before uses
#pragma unroll
        for (int j = 0; j < 4; ++j) {
            if (val[j]) {                     // uniform branch: masked stores
                float4* op = out4 + (size_t)idx[j] * D4 + lane;
                float4 r;
                r.x = (X[3 * j].x - m4.x) * s4.x;
                r.y = (X[3 * j].y - m4.y) * s4.y;
                r.z = (X[3 * j].z - m4.z) * s4.z;
                r.w = (X[3 * j].w - m4.w) * s4.w;
                op[0] = r;
                r.x = (X[3 * j + 1].x - m4.x) * s4.x;
                r.y = (X[3 * j + 1].y - m4.y) * s4.y;
                r.z = (X[3 * j + 1].z - m4.z) * s4.z;
                r.w = (X[3 * j + 1].w - m4.w) * s4.w;
                op[P4] = r;
                r.x = (X[3 * j + 2].x - m4.x) * s4.x;
                r.y = (X[3 * j + 2].y - m4.y) * s4.y;
                r.z = (X[3 * j + 2].z - m4.z) * s4.z;
                r.w = (X[3 * j + 2].w - m4.w) * s4.w;
                op[2 * P4] = r;
            }
        }
    }
}

extern "C" void kernel_launch(void* const* d_in, const int* in_sizes, int n_in,
                              void* d_out, int out_size, void* d_ws, size_t ws_size,
                              hipStream_t stream) {
    const float4* patches4 = (const float4*)d_in[0];
    const int*    pos_h    = (const int*)d_in[1];
    const int*    pos_w    = (const int*)d_in[2];
    const int*    mask     = (const int*)d_in[3];
    const float*  n_old    = (const float*)d_in[4];
    const float*  mean     = (const float*)d_in[5];
    const float*  m2       = (const float*)d_in[6];
    float4* out4 = (float4*)d_out;

    // workspace: ushort pf16[NTOK] (64 KB)
    unsigned short* pf16 = (unsigned short*)d_ws;

    k_pf<<<NTOK / 256, 256, 0, stream>>>(pos_h, pos_w, mask, pf16);
    k_cell<<<HW, 256, 0, stream>>>(patches4, pf16, n_old, mean, m2, out4);
}

// Round 10
// 58.574 us; speedup vs baseline: 1.1069x; 1.0139x over previous
//
#include <hip/hip_runtime.h>
#include <math.h>

// PatchNorm forward (training-mode Welford update + normalize), 2 kernels:
//   k_pf:   pack per-token cell id into ushort (0xFFFF = padded)
//   k_cell: one block per grid cell -- scan pf16 -> token list in LDS ->
//           gather rows via ASYNC global_load_lds pipeline (2 rows/wave in
//           flight, counted vmcnt waits) -> closed-form stats in LDS ->
//           normalize the SAME rows (L2-hot, 4-deep register batches).
// Round-9 lesson: register-batched loads can't give MLP -- the allocator
// (post-scheduler) reserialized them (VGPR 48). global_load_lds decouples
// in-flight loads from VGPRs: ~24 KB/CU in flight >> ~9 KB Little's-law
// requirement for 6.3 TB/s.
//
// Closed-form per-cell moments (n_g uniform within a cell):
//   mean_new = mo + (S1 - cnt*mo)/n_g                 S1 = sum_valid xbar
//   m2_new   = m2 + S2 - (mo+mn)*S1 + cnt*mo*mn       S2 = sum_valid xbar^2

#define EPSF 1e-6f

static constexpr int W_GRID  = 32;    // grid width (pf = pos_h*W + pos_w)
static constexpr int P2      = 256;   // patch_res^2
static constexpr int P4      = 64;    // P2/4
static constexpr int D4      = 192;   // D/4 float4 chunks per token
static constexpr int DDIM    = 768;   // floats per token row
static constexpr int HW      = 1024;  // grid cells
static constexpr int NTOK    = 32768; // tokens
static constexpr int LISTCAP = 96;    // token-list capacity (E[cnt]=28.8, max~50)
static constexpr int SLICE   = NTOK / HW; // 32 tokens/block for pad-zeroing

typedef const __attribute__((address_space(1))) void gas_void;
typedef __attribute__((address_space(3))) void       las_void;

// ---- kernel 1: pack per-token cell id (0xFFFF = padded) --------------------
__global__ void k_pf(const int* __restrict__ pos_h,
                     const int* __restrict__ pos_w,
                     const int* __restrict__ mask,
                     unsigned short* __restrict__ pf16) {
    int i = blockIdx.x * blockDim.x + threadIdx.x;
    if (i >= NTOK) return;
    const int valid = (mask[i] == 0);
    pf16[i] = valid ? (unsigned short)(pos_h[i] * W_GRID + pos_w[i])
                    : (unsigned short)0xFFFF;
}

// ---- kernel 2: fused per-cell moments + stats + normalize ------------------
__global__ void __launch_bounds__(256, 4)
k_cell(const float4* __restrict__ patches4,
       const unsigned short* __restrict__ pf16,
       const float* __restrict__ n_old,
       const float* __restrict__ mean_old,
       const float* __restrict__ m2_old,
       float4* __restrict__ out4) {
    const int g    = blockIdx.x;
    const int tid  = threadIdx.x;
    const int wave = tid >> 6;
    const int lane = tid & 63;

    __shared__ int            list[LISTCAP];
    __shared__ int            s_cnt;
    __shared__ unsigned short s_slice[SLICE];
    __shared__ float          stage_lds[4][2][DDIM];  // 24 KB: 2 rows/wave
    __shared__ float4         l14[4][64];
    __shared__ float4         l24[4][64];
    __shared__ float4         mn_s[P4];
    __shared__ float4         is_s[P4];

    if (tid == 0) s_cnt = 0;
    if (tid < SLICE) s_slice[tid] = pf16[g * SLICE + tid];

    // ---- issue ALL scan loads up front (16 independent L2 loads) -----------
    const int4* pp = (const int4*)pf16;
    int4 v[16];
#pragma unroll
    for (int it = 0; it < 16; ++it) v[it] = pp[it * 256 + tid];

    __syncthreads();

    // ---- pad-zeroing for this block's 32-token slice -----------------------
#pragma unroll
    for (int t = 0; t < SLICE; ++t) {
        if (s_slice[t] == 0xFFFF) {
            const int i = g * SLICE + t;
            if (tid < D4)
                out4[(size_t)i * D4 + tid] = make_float4(0.f, 0.f, 0.f, 0.f);
        }
    }

    // ---- process scan chunks -> LDS token list -----------------------------
#pragma unroll
    for (int it = 0; it < 16; ++it) {
        const int base = (it * 256 + tid) * 8;
#pragma unroll
        for (int k = 0; k < 4; ++k) {
            const int word = (&v[it].x)[k];
            const int g0 = word & 0xFFFF;
            const int g1 = (word >> 16) & 0xFFFF;
            if (g0 == g) { int s = atomicAdd(&s_cnt, 1); if (s < LISTCAP) list[s] = base + 2 * k; }
            if (g1 == g) { int s = atomicAdd(&s_cnt, 1); if (s < LISTCAP) list[s] = base + 2 * k + 1; }
        }
    }
    __syncthreads();
    const int c = min(s_cnt, LISTCAP);

    // ---- gather: async-staged pipeline, 2 rows/wave in flight --------------
    // wave handles rows kk = wave + 4*r, r in [0, nr)
    const int nr = (c > wave) ? ((c - wave + 3) >> 2) : 0;
    float*   my_stage = &stage_lds[wave][0][0];     // two 3KB slots

    // issue helper (inlined twice + loop): stage row r into slot (r&1)
    #define ISSUE_ROW(r)                                                      \
    do {                                                                      \
        const int kk_  = wave + 4 * (r);                                      \
        const int idx_ = list[kk_];                                           \
        const float* gb_ = ((const float*)patches4) + (size_t)idx_ * DDIM     \
                           + lane * 4;                                        \
        float* lb_ = my_stage + ((r) & 1) * DDIM;                             \
        __builtin_amdgcn_global_load_lds((gas_void*)(gb_),       (las_void*)(lb_),       16, 0, 0); \
        __builtin_amdgcn_global_load_lds((gas_void*)(gb_ + 256), (las_void*)(lb_ + 256), 16, 0, 0); \
        __builtin_amdgcn_global_load_lds((gas_void*)(gb_ + 512), (las_void*)(lb_ + 512), 16, 0, 0); \
    } while (0)

    if (nr > 0) ISSUE_ROW(0);
    if (nr > 1) ISSUE_ROW(1);

    float4 s1 = make_float4(0.f, 0.f, 0.f, 0.f);
    float4 s2 = make_float4(0.f, 0.f, 0.f, 0.f);
    for (int r = 0; r < nr; ++r) {
        if (r + 1 < nr) { asm volatile("s_waitcnt vmcnt(3)" ::: "memory"); }
        else            { asm volatile("s_waitcnt vmcnt(0)" ::: "memory"); }
        __builtin_amdgcn_sched_barrier(0);
        const float4* row = (const float4*)(my_stage + (r & 1) * DDIM);
        const float4 a = row[lane];
        const float4 b = row[lane + 64];
        const float4 d = row[lane + 128];
        float4 xb;
        xb.x = (a.x + b.x + d.x) * (1.0f / 3.0f);
        xb.y = (a.y + b.y + d.y) * (1.0f / 3.0f);
        xb.z = (a.z + b.z + d.z) * (1.0f / 3.0f);
        xb.w = (a.w + b.w + d.w) * (1.0f / 3.0f);
        s1.x += xb.x; s1.y += xb.y; s1.z += xb.z; s1.w += xb.w;
        s2.x += xb.x * xb.x; s2.y += xb.y * xb.y;
        s2.z += xb.z * xb.z; s2.w += xb.w * xb.w;
        __builtin_amdgcn_sched_barrier(0);   // keep DMA below the ds_read uses
        if (r + 2 < nr) ISSUE_ROW(r + 2);
    }
    #undef ISSUE_ROW

    // ---- cross-wave reduce + closed-form stats (tid = p index) -------------
    l14[wave][lane] = s1;
    l24[wave][lane] = s2;
    __syncthreads();

    {
        const float* l1f = (const float*)l14;
        const float* l2f = (const float*)l24;
        const float S1 = l1f[tid] + l1f[256 + tid] + l1f[512 + tid] + l1f[768 + tid];
        const float S2 = l2f[tid] + l2f[256 + tid] + l2f[512 + tid] + l2f[768 + tid];

        const float cnt = (float)c;
        const float nn  = n_old[g] + cnt;
        const float ng  = fmaxf(nn, 1.0f);
        const int   j   = g * P2 + tid;
        const float mo  = mean_old[j];
        const float mn  = mo + (S1 - cnt * mo) / ng;
        const float m2n = m2_old[j] + (S2 - (mo + mn) * S1 + cnt * mo * mn);
        const float var = (nn < 2.0f) ? 1.0f : (m2n / ng);
        ((float*)mn_s)[tid] = mn;
        ((float*)is_s)[tid] = 1.0f / (sqrtf(var) + EPSF);
    }
    __syncthreads();

    // ---- normalize the same rows (L2-hot), 4 tokens per batch --------------
    const float4 m4 = mn_s[lane];
    const float4 s4 = is_s[lane];
    for (int k = wave; k < c; k += 16) {
        int  idx[4];
        bool val[4];
#pragma unroll
        for (int j = 0; j < 4; ++j) {
            const int kk = k + 4 * j;
            val[j] = (kk < c);                // wave-uniform predicate
            idx[j] = list[val[j] ? kk : k];
        }
        float4 X[12];
#pragma unroll
        for (int j = 0; j < 4; ++j) {
            const float4* tp = patches4 + (size_t)idx[j] * D4 + lane;
            X[3 * j]     = tp[0];
            X[3 * j + 1] = tp[P4];
            X[3 * j + 2] = tp[2 * P4];
        }
        __builtin_amdgcn_sched_barrier(0);
#pragma unroll
        for (int j = 0; j < 4; ++j) {
            if (val[j]) {                     // uniform branch: masked stores
                float4* op = out4 + (size_t)idx[j] * D4 + lane;
                float4 r;
                r.x = (X[3 * j].x - m4.x) * s4.x;
                r.y = (X[3 * j].y - m4.y) * s4.y;
                r.z = (X[3 * j].z - m4.z) * s4.z;
                r.w = (X[3 * j].w - m4.w) * s4.w;
                op[0] = r;
                r.x = (X[3 * j + 1].x - m4.x) * s4.x;
                r.y = (X[3 * j + 1].y - m4.y) * s4.y;
                r.z = (X[3 * j + 1].z - m4.z) * s4.z;
                r.w = (X[3 * j + 1].w - m4.w) * s4.w;
                op[P4] = r;
                r.x = (X[3 * j + 2].x - m4.x) * s4.x;
                r.y = (X[3 * j + 2].y - m4.y) * s4.y;
                r.z = (X[3 * j + 2].z - m4.z) * s4.z;
                r.w = (X[3 * j + 2].w - m4.w) * s4.w;
                op[2 * P4] = r;
            }
        }
    }
}

extern "C" void kernel_launch(void* const* d_in, const int* in_sizes, int n_in,
                              void* d_out, int out_size, void* d_ws, size_t ws_size,
                              hipStream_t stream) {
    const float4* patches4 = (const float4*)d_in[0];
    const int*    pos_h    = (const int*)d_in[1];
    const int*    pos_w    = (const int*)d_in[2];
    const int*    mask     = (const int*)d_in[3];
    const float*  n_old    = (const float*)d_in[4];
    const float*  mean     = (const float*)d_in[5];
    const float*  m2       = (const float*)d_in[6];
    float4* out4 = (float4*)d_out;

    // workspace: ushort pf16[NTOK] (64 KB)
    unsigned short* pf16 = (unsigned short*)d_ws;

    k_pf<<<NTOK / 256, 256, 0, stream>>>(pos_h, pos_w, mask, pf16);
    k_cell<<<HW, 256, 0, stream>>>(patches4, pf16, n_old, mean, m2, out4);
}